// Round 1
// baseline (1605.050 us; speedup 1.0000x reference)
//
#include <hip/hip_runtime.h>
#include <hip/hip_bf16.h>

#define B_   4
#define N_   4096
#define D_   128
#define PH_  32
#define AH_  256
#define K_   16
#define BN_  (B_*N_)

__device__ inline unsigned long long shfl_xor_u64(unsigned long long v, int m) {
  int lo = (int)(unsigned)(v & 0xffffffffull);
  int hi = (int)(unsigned)(v >> 32);
  lo = __shfl_xor(lo, m, 64);
  hi = __shfl_xor(hi, m, 64);
  return ((unsigned long long)(unsigned)hi << 32) | (unsigned)lo;
}

__device__ inline float f4c(const float4& v, int i) {
  return i == 0 ? v.x : i == 1 ? v.y : i == 2 ? v.z : v.w;
}

// ---------------- K1: q/k/v projections (fp32, register-tiled) ----------------
__global__ __launch_bounds__(256) void qkv_kernel(
    const float* __restrict__ x,
    const float* __restrict__ Wq, const float* __restrict__ Wk, const float* __restrict__ Wv,
    float* __restrict__ xq, float* __restrict__ xk, float* __restrict__ xv)
{
  __shared__ float xs[32][132];
  const int t = threadIdx.x;
  const int r0 = blockIdx.x * 32;
  for (int e = t; e < 32 * 128; e += 256) xs[e >> 7][e & 127] = x[(size_t)r0 * 128 + e];
  __syncthreads();

  const int rg = t >> 5, cg = t & 31;
  const int rr0 = rg * 4, j0 = cg * 4;
  const float* Ws[3] = {Wq, Wk, Wv};
  float* outs[3] = {xq, xk, xv};

  #pragma unroll
  for (int m = 0; m < 3; ++m) {
    const float* __restrict__ W = Ws[m];
    float acc[4][4];
    #pragma unroll
    for (int a = 0; a < 4; ++a)
      #pragma unroll
      for (int bb = 0; bb < 4; ++bb) acc[a][bb] = 0.f;

    for (int c0 = 0; c0 < 128; c0 += 4) {
      float4 xv4[4];
      #pragma unroll
      for (int a = 0; a < 4; ++a) xv4[a] = *(const float4*)&xs[rr0 + a][c0];
      #pragma unroll
      for (int cc = 0; cc < 4; ++cc) {
        float4 w4 = *(const float4*)&W[(size_t)(c0 + cc) * 128 + j0];
        #pragma unroll
        for (int a = 0; a < 4; ++a) {
          float xvv = f4c(xv4[a], cc);
          acc[a][0] = fmaf(xvv, w4.x, acc[a][0]);
          acc[a][1] = fmaf(xvv, w4.y, acc[a][1]);
          acc[a][2] = fmaf(xvv, w4.z, acc[a][2]);
          acc[a][3] = fmaf(xvv, w4.w, acc[a][3]);
        }
      }
    }
    #pragma unroll
    for (int a = 0; a < 4; ++a) {
      float4 o = make_float4(acc[a][0], acc[a][1], acc[a][2], acc[a][3]);
      *(float4*)&outs[m][(size_t)(r0 + rr0 + a) * 128 + j0] = o;
    }
  }
}

// ---------------- K2: brute-force kNN (exact fp32 arithmetic, tie -> lower idx) ----------------
__global__ __launch_bounds__(256) void knn_kernel(const float* __restrict__ pos,
                                                  int* __restrict__ knn)
{
  __shared__ unsigned long long cand[4][16][64];
  const int wv = threadIdx.x >> 6, lane = threadIdx.x & 63;
  const int q = blockIdx.x * 4 + wv;
  const int b = q >> 12, i = q & (N_ - 1);
  const float* __restrict__ pb = pos + (size_t)b * N_ * 3;
  const float qx = pb[i * 3 + 0], qy = pb[i * 3 + 1], qz = pb[i * 3 + 2];

  #pragma unroll
  for (int s = 0; s < 16; ++s) cand[wv][s][lane] = ~0ull;
  unsigned long long worst = ~0ull;

  for (int m = 0; m < N_ / 64; ++m) {
    const int j = m * 64 + lane;
    float dx = qx - pb[j * 3 + 0];
    float dy = qy - pb[j * 3 + 1];
    float dz = qz - pb[j * 3 + 2];
    // ((dx^2 + dy^2) + dz^2) with rounding ops that cannot be FMA-contracted:
    float d2 = __fadd_rn(__fadd_rn(__fmul_rn(dx, dx), __fmul_rn(dy, dy)), __fmul_rn(dz, dz));
    unsigned long long key =
        ((unsigned long long)__float_as_uint(d2) << 32) | (unsigned)j;
    if (key < worst) {
      int s = 15;
      while (s > 0 && cand[wv][s - 1][lane] > key) {
        cand[wv][s][lane] = cand[wv][s - 1][lane];
        --s;
      }
      cand[wv][s][lane] = key;
      worst = cand[wv][15][lane];
    }
  }

  // merge 64 sorted lists: 16 rounds of butterfly-min over heads
  int p = 0;
  unsigned long long head = cand[wv][0][lane];
  for (int r = 0; r < K_; ++r) {
    unsigned long long mn = head;
    #pragma unroll
    for (int off = 32; off > 0; off >>= 1) {
      unsigned long long o = shfl_xor_u64(mn, off);
      mn = (o < mn) ? o : mn;
    }
    if (head == mn) { ++p; head = (p < 16) ? cand[wv][p][lane] : ~0ull; }
    if (lane == 0) knn[(size_t)q * K_ + r] = (int)(unsigned)(mn & 0xffffffffull);
  }
}

// ---------------- K3: fused pos-MLP + attn-MLP + softmax + aggregation ----------------
__global__ __launch_bounds__(256) void fused_kernel(
    const float* __restrict__ pos,
    const float* __restrict__ xq, const float* __restrict__ xk, const float* __restrict__ xv,
    const int* __restrict__ knn,
    const float* __restrict__ p_w1, const float* __restrict__ p_b1,
    const float* __restrict__ p_w2, const float* __restrict__ p_b2,
    const float* __restrict__ a_w1, const float* __restrict__ a_b1,
    const float* __restrict__ a_w2, const float* __restrict__ a_b2,
    float* __restrict__ out)
{
  __shared__ float q_s[128];
  __shared__ int   idx_s[16];
  __shared__ float rel_s[16][3];
  __shared__ float hid_s[16][32];
  __shared__ float pe_s[16][132];
  __shared__ float h_s[16][132];
  __shared__ float t1_s[16][260];
  __shared__ float ap_s[16][132];

  const int bn = blockIdx.x;
  const int b = bn >> 12;
  const int t = threadIdx.x;

  if (t < 128) q_s[t] = xq[(size_t)bn * 128 + t];
  if (t < 16)  idx_s[t] = knn[(size_t)bn * 16 + t];
  __syncthreads();
  if (t < 48) {
    int k = t / 3, c = t % 3;
    rel_s[k][c] = pos[(size_t)bn * 3 + c] - pos[((size_t)b * N_ + idx_s[k]) * 3 + c];
  }
  __syncthreads();

  // hidden = relu(rel @ p_w1 + p_b1): 16x32
  #pragma unroll
  for (int rep = 0; rep < 2; ++rep) {
    int e = t + rep * 256;
    int k = e >> 5, hh = e & 31;
    float acc = p_b1[hh];
    acc = fmaf(rel_s[k][0], p_w1[0 * PH_ + hh], acc);
    acc = fmaf(rel_s[k][1], p_w1[1 * PH_ + hh], acc);
    acc = fmaf(rel_s[k][2], p_w1[2 * PH_ + hh], acc);
    hid_s[k][hh] = fmaxf(acc, 0.f);
  }
  __syncthreads();

  // pe = hidden @ p_w2 + p_b2 ; h = q - k_gathered + pe   (16x128)
  {
    const int d = t & 127;
    #pragma unroll
    for (int rep = 0; rep < 8; ++rep) {
      int k = rep * 2 + (t >> 7);
      float acc = p_b2[d];
      #pragma unroll
      for (int hh = 0; hh < 32; ++hh) acc = fmaf(hid_s[k][hh], p_w2[hh * 128 + d], acc);
      pe_s[k][d] = acc;
      h_s[k][d] = q_s[d] - xk[((size_t)b * N_ + idx_s[k]) * 128 + d] + acc;
    }
  }
  __syncthreads();

  // C: t1 = relu(h @ a_w1 + a_b1): 16x256, thread tile 2k x 8j
  {
    const int kg = t & 7, jg = t >> 3;   // kg 0..7, jg 0..31
    const int k0 = kg * 2, j0 = jg * 8;
    float acc[2][8];
    #pragma unroll
    for (int a = 0; a < 2; ++a)
      #pragma unroll
      for (int j = 0; j < 8; ++j) acc[a][j] = 0.f;

    for (int c0 = 0; c0 < 128; c0 += 4) {
      float4 h4[2];
      h4[0] = *(const float4*)&h_s[k0][c0];
      h4[1] = *(const float4*)&h_s[k0 + 1][c0];
      #pragma unroll
      for (int cc = 0; cc < 4; ++cc) {
        float4 wA = *(const float4*)&a_w1[(size_t)(c0 + cc) * 256 + j0];
        float4 wB = *(const float4*)&a_w1[(size_t)(c0 + cc) * 256 + j0 + 4];
        float h0 = f4c(h4[0], cc), h1 = f4c(h4[1], cc);
        acc[0][0] = fmaf(h0, wA.x, acc[0][0]); acc[0][1] = fmaf(h0, wA.y, acc[0][1]);
        acc[0][2] = fmaf(h0, wA.z, acc[0][2]); acc[0][3] = fmaf(h0, wA.w, acc[0][3]);
        acc[0][4] = fmaf(h0, wB.x, acc[0][4]); acc[0][5] = fmaf(h0, wB.y, acc[0][5]);
        acc[0][6] = fmaf(h0, wB.z, acc[0][6]); acc[0][7] = fmaf(h0, wB.w, acc[0][7]);
        acc[1][0] = fmaf(h1, wA.x, acc[1][0]); acc[1][1] = fmaf(h1, wA.y, acc[1][1]);
        acc[1][2] = fmaf(h1, wA.z, acc[1][2]); acc[1][3] = fmaf(h1, wA.w, acc[1][3]);
        acc[1][4] = fmaf(h1, wB.x, acc[1][4]); acc[1][5] = fmaf(h1, wB.y, acc[1][5]);
        acc[1][6] = fmaf(h1, wB.z, acc[1][6]); acc[1][7] = fmaf(h1, wB.w, acc[1][7]);
      }
    }
    #pragma unroll
    for (int a = 0; a < 2; ++a) {
      float4 oA, oB;
      oA.x = fmaxf(acc[a][0] + a_b1[j0 + 0], 0.f);
      oA.y = fmaxf(acc[a][1] + a_b1[j0 + 1], 0.f);
      oA.z = fmaxf(acc[a][2] + a_b1[j0 + 2], 0.f);
      oA.w = fmaxf(acc[a][3] + a_b1[j0 + 3], 0.f);
      oB.x = fmaxf(acc[a][4] + a_b1[j0 + 4], 0.f);
      oB.y = fmaxf(acc[a][5] + a_b1[j0 + 5], 0.f);
      oB.z = fmaxf(acc[a][6] + a_b1[j0 + 6], 0.f);
      oB.w = fmaxf(acc[a][7] + a_b1[j0 + 7], 0.f);
      *(float4*)&t1_s[k0 + a][j0]     = oA;
      *(float4*)&t1_s[k0 + a][j0 + 4] = oB;
    }
  }
  __syncthreads();

  // D: ap = t1 @ a_w2 + a_b2: 16x128, thread tile 2k x 4d
  {
    const int kg = t >> 5, dg = t & 31;   // kg 0..7, dg 0..31
    const int k0 = kg * 2, d0 = dg * 4;
    float acc[2][4];
    #pragma unroll
    for (int a = 0; a < 2; ++a)
      #pragma unroll
      for (int j = 0; j < 4; ++j) acc[a][j] = 0.f;

    for (int j0 = 0; j0 < 256; j0 += 4) {
      float4 t4[2];
      t4[0] = *(const float4*)&t1_s[k0][j0];
      t4[1] = *(const float4*)&t1_s[k0 + 1][j0];
      #pragma unroll
      for (int jj = 0; jj < 4; ++jj) {
        float4 w4 = *(const float4*)&a_w2[(size_t)(j0 + jj) * 128 + d0];
        float ta = f4c(t4[0], jj), tb = f4c(t4[1], jj);
        acc[0][0] = fmaf(ta, w4.x, acc[0][0]); acc[0][1] = fmaf(ta, w4.y, acc[0][1]);
        acc[0][2] = fmaf(ta, w4.z, acc[0][2]); acc[0][3] = fmaf(ta, w4.w, acc[0][3]);
        acc[1][0] = fmaf(tb, w4.x, acc[1][0]); acc[1][1] = fmaf(tb, w4.y, acc[1][1]);
        acc[1][2] = fmaf(tb, w4.z, acc[1][2]); acc[1][3] = fmaf(tb, w4.w, acc[1][3]);
      }
    }
    #pragma unroll
    for (int a = 0; a < 2; ++a) {
      float4 o;
      o.x = acc[a][0] + a_b2[d0 + 0];
      o.y = acc[a][1] + a_b2[d0 + 1];
      o.z = acc[a][2] + a_b2[d0 + 2];
      o.w = acc[a][3] + a_b2[d0 + 3];
      *(float4*)&ap_s[k0 + a][d0] = o;
    }
  }
  __syncthreads();

  // E: softmax over K (per channel d) + aggregation
  if (t < 128) {
    const int d = t;
    const float scale = 0.08838834764831845f;  // 1/sqrt(128)
    float lg[16];
    float mx = -1e30f;
    #pragma unroll
    for (int k = 0; k < 16; ++k) { lg[k] = ap_s[k][d] * scale; mx = fmaxf(mx, lg[k]); }
    float den = 0.f;
    #pragma unroll
    for (int k = 0; k < 16; ++k) { lg[k] = expf(lg[k] - mx); den += lg[k]; }
    float inv = 1.f / den;
    float agg = 0.f;
    #pragma unroll
    for (int k = 0; k < 16; ++k) {
      float vv = xv[((size_t)b * N_ + idx_s[k]) * 128 + d] + pe_s[k][d];
      agg = fmaf(lg[k] * inv, vv, agg);
    }
    out[(size_t)bn * 128 + d] = agg;
  }
}

extern "C" void kernel_launch(void* const* d_in, const int* in_sizes, int n_in,
                              void* d_out, int out_size, void* d_ws, size_t ws_size,
                              hipStream_t stream)
{
  const float* x    = (const float*)d_in[0];
  const float* pos  = (const float*)d_in[1];
  const float* Wq   = (const float*)d_in[2];
  const float* Wk   = (const float*)d_in[3];
  const float* Wv   = (const float*)d_in[4];
  const float* p_w1 = (const float*)d_in[5];
  const float* p_b1 = (const float*)d_in[6];
  const float* p_w2 = (const float*)d_in[7];
  const float* p_b2 = (const float*)d_in[8];
  const float* a_w1 = (const float*)d_in[9];
  const float* a_b1 = (const float*)d_in[10];
  const float* a_w2 = (const float*)d_in[11];
  const float* a_b2 = (const float*)d_in[12];
  float* out = (float*)d_out;

  float* xq = (float*)d_ws;
  float* xk = xq + (size_t)BN_ * 128;
  float* xv = xk + (size_t)BN_ * 128;
  int*   knn = (int*)(xv + (size_t)BN_ * 128);

  qkv_kernel<<<BN_ / 32, 256, 0, stream>>>(x, Wq, Wk, Wv, xq, xk, xv);
  knn_kernel<<<BN_ / 4, 256, 0, stream>>>(pos, knn);
  fused_kernel<<<BN_, 256, 0, stream>>>(pos, xq, xk, xv, knn,
                                        p_w1, p_b1, p_w2, p_b2,
                                        a_w1, a_b1, a_w2, a_b2, out);
}

// Round 2
// 600.083 us; speedup vs baseline: 2.6747x; 2.6747x over previous
//
#include <hip/hip_runtime.h>
#include <hip/hip_bf16.h>

#define B_   4
#define N_   4096
#define D_   128
#define PH_  32
#define AH_  256
#define K_   16
#define BN_  (B_*N_)

typedef __attribute__((ext_vector_type(8))) short short8;
typedef __attribute__((ext_vector_type(4))) float f32x4;

__device__ inline unsigned long long shfl_xor_u64(unsigned long long v, int m) {
  int lo = (int)(unsigned)(v & 0xffffffffull);
  int hi = (int)(unsigned)(v >> 32);
  lo = __shfl_xor(lo, m, 64);
  hi = __shfl_xor(hi, m, 64);
  return ((unsigned long long)(unsigned)hi << 32) | (unsigned)lo;
}

__device__ inline float f4c(const float4& v, int i) {
  return i == 0 ? v.x : i == 1 ? v.y : i == 2 ? v.z : v.w;
}

__device__ inline unsigned short f2bf(float f) {
  unsigned u = __float_as_uint(f);
  unsigned r = u + 0x7fffu + ((u >> 16) & 1u);   // round-to-nearest-even
  return (unsigned short)(r >> 16);
}

// ---------------- K0: shuffle weights into bf16 B-fragment layout ----------------
// B-fragment convention (mfma_f32_16x16x32_bf16): lane l holds B[k = 32*kc + 8*(l>>4)+j][col = 16*nt + (l&15)],
// j = 0..7 contiguous. Stored so each lane does one coalesced 16B load per fragment.
__global__ __launch_bounds__(256) void wshuf_kernel(
    const float* __restrict__ a_w1, const float* __restrict__ a_w2,
    unsigned short* __restrict__ W1f, unsigned short* __restrict__ W2f)
{
  int tid = blockIdx.x * blockDim.x + threadIdx.x;
  for (int f = tid; f < 4096; f += blockDim.x * gridDim.x) {
    int lane = f & 63, g = lane >> 4, c = lane & 15;
    {
      int nt = f >> 8, kc = (f >> 6) & 3;           // W1: K=128 (4 kc), N=256 (16 nt)
      unsigned short o[8];
      #pragma unroll
      for (int j = 0; j < 8; ++j)
        o[j] = f2bf(a_w1[(size_t)(32 * kc + 8 * g + j) * 256 + 16 * nt + c]);
      #pragma unroll
      for (int j = 0; j < 8; ++j) W1f[(size_t)f * 8 + j] = o[j];
    }
    {
      int nt = f >> 9, kc = (f >> 6) & 7;           // W2: K=256 (8 kc), N=128 (8 nt)
      unsigned short o[8];
      #pragma unroll
      for (int j = 0; j < 8; ++j)
        o[j] = f2bf(a_w2[(size_t)(32 * kc + 8 * g + j) * 128 + 16 * nt + c]);
      #pragma unroll
      for (int j = 0; j < 8; ++j) W2f[(size_t)f * 8 + j] = o[j];
    }
  }
}

// ---------------- K1: q/k/v projections (fp32, register-tiled) ----------------
__global__ __launch_bounds__(256) void qkv_kernel(
    const float* __restrict__ x,
    const float* __restrict__ Wq, const float* __restrict__ Wk, const float* __restrict__ Wv,
    float* __restrict__ xq, float* __restrict__ xk, float* __restrict__ xv)
{
  __shared__ float xs[32][132];
  const int t = threadIdx.x;
  const int r0 = blockIdx.x * 32;
  for (int e = t; e < 32 * 128; e += 256) xs[e >> 7][e & 127] = x[(size_t)r0 * 128 + e];
  __syncthreads();

  const int rg = t >> 5, cg = t & 31;
  const int rr0 = rg * 4, j0 = cg * 4;
  const float* Ws[3] = {Wq, Wk, Wv};
  float* outs[3] = {xq, xk, xv};

  #pragma unroll
  for (int m = 0; m < 3; ++m) {
    const float* __restrict__ W = Ws[m];
    float acc[4][4];
    #pragma unroll
    for (int a = 0; a < 4; ++a)
      #pragma unroll
      for (int bb = 0; bb < 4; ++bb) acc[a][bb] = 0.f;

    for (int c0 = 0; c0 < 128; c0 += 4) {
      float4 xv4[4];
      #pragma unroll
      for (int a = 0; a < 4; ++a) xv4[a] = *(const float4*)&xs[rr0 + a][c0];
      #pragma unroll
      for (int cc = 0; cc < 4; ++cc) {
        float4 w4 = *(const float4*)&W[(size_t)(c0 + cc) * 128 + j0];
        #pragma unroll
        for (int a = 0; a < 4; ++a) {
          float xvv = f4c(xv4[a], cc);
          acc[a][0] = fmaf(xvv, w4.x, acc[a][0]);
          acc[a][1] = fmaf(xvv, w4.y, acc[a][1]);
          acc[a][2] = fmaf(xvv, w4.z, acc[a][2]);
          acc[a][3] = fmaf(xvv, w4.w, acc[a][3]);
        }
      }
    }
    #pragma unroll
    for (int a = 0; a < 4; ++a) {
      float4 o = make_float4(acc[a][0], acc[a][1], acc[a][2], acc[a][3]);
      *(float4*)&outs[m][(size_t)(r0 + rr0 + a) * 128 + j0] = o;
    }
  }
}

// ---------------- K2: brute-force kNN (exact fp32 arithmetic, tie -> lower idx) ----------------
__global__ __launch_bounds__(256) void knn_kernel(const float* __restrict__ pos,
                                                  int* __restrict__ knn)
{
  __shared__ unsigned long long cand[4][16][64];
  const int wv = threadIdx.x >> 6, lane = threadIdx.x & 63;
  const int q = blockIdx.x * 4 + wv;
  const int b = q >> 12, i = q & (N_ - 1);
  const float* __restrict__ pb = pos + (size_t)b * N_ * 3;
  const float qx = pb[i * 3 + 0], qy = pb[i * 3 + 1], qz = pb[i * 3 + 2];

  #pragma unroll
  for (int s = 0; s < 16; ++s) cand[wv][s][lane] = ~0ull;
  unsigned long long worst = ~0ull;

  for (int m = 0; m < N_ / 64; ++m) {
    const int j = m * 64 + lane;
    float dx = qx - pb[j * 3 + 0];
    float dy = qy - pb[j * 3 + 1];
    float dz = qz - pb[j * 3 + 2];
    float d2 = __fadd_rn(__fadd_rn(__fmul_rn(dx, dx), __fmul_rn(dy, dy)), __fmul_rn(dz, dz));
    unsigned long long key =
        ((unsigned long long)__float_as_uint(d2) << 32) | (unsigned)j;
    if (key < worst) {
      int s = 15;
      while (s > 0 && cand[wv][s - 1][lane] > key) {
        cand[wv][s][lane] = cand[wv][s - 1][lane];
        --s;
      }
      cand[wv][s][lane] = key;
      worst = cand[wv][15][lane];
    }
  }

  int p = 0;
  unsigned long long head = cand[wv][0][lane];
  for (int r = 0; r < K_; ++r) {
    unsigned long long mn = head;
    #pragma unroll
    for (int off = 32; off > 0; off >>= 1) {
      unsigned long long o = shfl_xor_u64(mn, off);
      mn = (o < mn) ? o : mn;
    }
    if (head == mn) { ++p; head = (p < 16) ? cand[wv][p][lane] : ~0ull; }
    if (lane == 0) knn[(size_t)q * K_ + r] = (int)(unsigned)(mn & 0xffffffffull);
  }
}

// ---------------- K3a: pos-MLP; emit H (bf16 A-fragment layout) and VPE (fp32 agg layout) ----------------
// Hf:  lane l of fragment (point p, kc) holds H[row=l&15][k=32*kc+8*(l>>4)+j], j=0..7.
// VPEf: lane l of fragment (point p, nt) holds VPE[row=4*(l>>4)+r][col=16*nt+(l&15)], r=0..3 (float4).
__global__ __launch_bounds__(256) void build_kernel(
    const float* __restrict__ pos,
    const float* __restrict__ xq, const float* __restrict__ xk, const float* __restrict__ xv,
    const int* __restrict__ knn,
    const float* __restrict__ p_w1, const float* __restrict__ p_b1,
    const float* __restrict__ p_w2, const float* __restrict__ p_b2,
    unsigned short* __restrict__ Hf, float* __restrict__ VPEf)
{
  __shared__ int   idx_s[4][16];
  __shared__ float rel_s[4][16][3];
  __shared__ float hid_s[4][16][32];
  __shared__ float pe_s[4][16][132];
  __shared__ float q_s[4][128];

  const int pb = blockIdx.x * 4;
  const int b = pb >> 12;
  const int t = threadIdx.x;

  if (t < 64) idx_s[t >> 4][t & 15] = knn[(size_t)(pb + (t >> 4)) * 16 + (t & 15)];
  {
    int e = t;          q_s[e >> 7][e & 127] = xq[(size_t)pb * 128 + e];
    e = t + 256;        q_s[e >> 7][e & 127] = xq[(size_t)pb * 128 + e];
  }
  __syncthreads();
  if (t < 192) {
    int p = t / 48, r = (t / 3) % 16, c = t % 3;
    rel_s[p][r][c] = pos[(size_t)(pb + p) * 3 + c] - pos[((size_t)b * N_ + idx_s[p][r]) * 3 + c];
  }
  __syncthreads();

  #pragma unroll
  for (int rep = 0; rep < 8; ++rep) {
    int e = rep * 256 + t;
    int p = e >> 9, r = (e >> 5) & 15, hh = e & 31;
    float acc = p_b1[hh];
    acc = fmaf(rel_s[p][r][0], p_w1[0 * PH_ + hh], acc);
    acc = fmaf(rel_s[p][r][1], p_w1[1 * PH_ + hh], acc);
    acc = fmaf(rel_s[p][r][2], p_w1[2 * PH_ + hh], acc);
    hid_s[p][r][hh] = fmaxf(acc, 0.f);
  }
  __syncthreads();

  #pragma unroll
  for (int rep = 0; rep < 32; ++rep) {
    int e = rep * 256 + t;
    int p = e >> 11, r = (e >> 7) & 15, d = e & 127;
    float acc = p_b2[d];
    #pragma unroll
    for (int hh = 0; hh < 32; ++hh) acc = fmaf(hid_s[p][r][hh], p_w2[hh * 128 + d], acc);
    pe_s[p][r][d] = acc;
  }
  __syncthreads();

  // H fragments
  #pragma unroll
  for (int rep = 0; rep < 4; ++rep) {
    int e = rep * 256 + t;
    int p = e >> 8, kc = (e >> 6) & 3, lane = e & 63;
    int g = lane >> 4, row = lane & 15;
    int k0 = 32 * kc + 8 * g;
    const float* krow = xk + ((size_t)b * N_ + idx_s[p][row]) * 128 + k0;
    float4 k4a = *(const float4*)(krow);
    float4 k4b = *(const float4*)(krow + 4);
    unsigned short o[8];
    #pragma unroll
    for (int j = 0; j < 8; ++j) {
      float kv = j < 4 ? f4c(k4a, j) : f4c(k4b, j - 4);
      float h = q_s[p][k0 + j] - kv + pe_s[p][row][k0 + j];
      o[j] = f2bf(h);
    }
    unsigned short* dst = Hf + ((size_t)(pb + p) * 4 + kc) * 512 + (size_t)lane * 8;
    #pragma unroll
    for (int j = 0; j < 8; ++j) dst[j] = o[j];
  }

  // VPE fragments (fp32)
  #pragma unroll
  for (int rep = 0; rep < 8; ++rep) {
    int e = rep * 256 + t;
    int p = e >> 9, nt = (e >> 6) & 7, lane = e & 63;
    int g = lane >> 4, c = lane & 15;
    float4 o;
    #pragma unroll
    for (int r = 0; r < 4; ++r) {
      int row = g * 4 + r;
      int col = 16 * nt + c;
      float vv = xv[((size_t)b * N_ + idx_s[p][row]) * 128 + col] + pe_s[p][row][col];
      if (r == 0) o.x = vv; else if (r == 1) o.y = vv; else if (r == 2) o.z = vv; else o.w = vv;
    }
    *(float4*)(VPEf + (((size_t)(pb + p) * 8 + nt) * 64 + lane) * 4) = o;
  }
}

// ---------------- K3b: MFMA attn-MLP + softmax + aggregation (one point per wave) ----------------
__global__ __launch_bounds__(512) void mlp_kernel(
    const unsigned short* __restrict__ Hf,
    const unsigned short* __restrict__ W1f, const unsigned short* __restrict__ W2f,
    const float* __restrict__ a_b1, const float* __restrict__ a_b2,
    const float* __restrict__ VPEf,
    float* __restrict__ out)
{
  __shared__ unsigned short t1s[8][16][136];   // per-wave private T1 half-tile (pad 136 -> 2-way-free)

  const int w = threadIdx.x >> 6, lane = threadIdx.x & 63;
  const int g = lane >> 4, c = lane & 15;
  const size_t p = (size_t)blockIdx.x * 8 + w;

  short8 ha[4];
  #pragma unroll
  for (int kc = 0; kc < 4; ++kc)
    ha[kc] = *(const short8*)(Hf + (p * 4 + kc) * 512 + (size_t)lane * 8);

  f32x4 acc2[8];
  #pragma unroll
  for (int i = 0; i < 8; ++i) acc2[i] = (f32x4){0.f, 0.f, 0.f, 0.f};

  #pragma unroll
  for (int half = 0; half < 2; ++half) {
    f32x4 acc1[8];
    #pragma unroll
    for (int i = 0; i < 8; ++i) acc1[i] = (f32x4){0.f, 0.f, 0.f, 0.f};

    // GEMM1 half: T1[:, half*128 .. half*128+127]
    #pragma unroll
    for (int ntl = 0; ntl < 8; ++ntl) {
      const unsigned short* wb = W1f + (size_t)(half * 8 + ntl) * 2048 + (size_t)lane * 8;
      #pragma unroll
      for (int kc = 0; kc < 4; ++kc) {
        short8 bf = *(const short8*)(wb + (size_t)kc * 512);
        acc1[ntl] = __builtin_amdgcn_mfma_f32_16x16x32_bf16(ha[kc], bf, acc1[ntl], 0, 0, 0);
      }
    }
    // bias + relu + store bf16 to wave-private LDS
    #pragma unroll
    for (int ntl = 0; ntl < 8; ++ntl) {
      float b1v = a_b1[(half * 8 + ntl) * 16 + c];
      #pragma unroll
      for (int r = 0; r < 4; ++r) {
        float vv = acc1[ntl][r] + b1v;
        vv = fmaxf(vv, 0.f);
        t1s[w][g * 4 + r][ntl * 16 + c] = f2bf(vv);
      }
    }
    // GEMM2 partial: K-chunk = this half's 128 cols of T1
    #pragma unroll
    for (int kc2 = 0; kc2 < 4; ++kc2) {
      short8 a2 = *(const short8*)&t1s[w][c][kc2 * 32 + g * 8];
      const unsigned short* w2b = W2f + (size_t)(half * 4 + kc2) * 512 + (size_t)lane * 8;
      #pragma unroll
      for (int nt2 = 0; nt2 < 8; ++nt2) {
        short8 b2f = *(const short8*)(w2b + (size_t)nt2 * 4096);
        acc2[nt2] = __builtin_amdgcn_mfma_f32_16x16x32_bf16(a2, b2f, acc2[nt2], 0, 0, 0);
      }
    }
  }

  // epilogue: bias, softmax over the 16 rows (per column), aggregate with VPE
  const float scale = 0.08838834764831845f;   // 1/sqrt(128)
  #pragma unroll
  for (int nt2 = 0; nt2 < 8; ++nt2) {
    float b2v = a_b2[nt2 * 16 + c];
    float l0 = acc2[nt2][0] + b2v;
    float l1 = acc2[nt2][1] + b2v;
    float l2 = acc2[nt2][2] + b2v;
    float l3 = acc2[nt2][3] + b2v;
    float mx = fmaxf(fmaxf(l0, l1), fmaxf(l2, l3));
    mx = fmaxf(mx, __shfl_xor(mx, 16, 64));
    mx = fmaxf(mx, __shfl_xor(mx, 32, 64));
    float e0 = expf((l0 - mx) * scale);
    float e1 = expf((l1 - mx) * scale);
    float e2 = expf((l2 - mx) * scale);
    float e3 = expf((l3 - mx) * scale);
    float s = e0 + e1 + e2 + e3;
    s += __shfl_xor(s, 16, 64);
    s += __shfl_xor(s, 32, 64);
    float inv = 1.f / s;
    float4 vp = *(const float4*)(VPEf + ((p * 8 + nt2) * 64 + lane) * 4);
    float ac = (e0 * vp.x + e1 * vp.y + e2 * vp.z + e3 * vp.w) * inv;
    ac += __shfl_xor(ac, 16, 64);
    ac += __shfl_xor(ac, 32, 64);
    if (g == 0) out[p * 128 + nt2 * 16 + c] = ac;
  }
}

extern "C" void kernel_launch(void* const* d_in, const int* in_sizes, int n_in,
                              void* d_out, int out_size, void* d_ws, size_t ws_size,
                              hipStream_t stream)
{
  const float* x    = (const float*)d_in[0];
  const float* pos  = (const float*)d_in[1];
  const float* Wq   = (const float*)d_in[2];
  const float* Wk   = (const float*)d_in[3];
  const float* Wv   = (const float*)d_in[4];
  const float* p_w1 = (const float*)d_in[5];
  const float* p_b1 = (const float*)d_in[6];
  const float* p_w2 = (const float*)d_in[7];
  const float* p_b2 = (const float*)d_in[8];
  const float* a_w1 = (const float*)d_in[9];
  const float* a_b1 = (const float*)d_in[10];
  const float* a_w2 = (const float*)d_in[11];
  const float* a_b2 = (const float*)d_in[12];
  float* out = (float*)d_out;

  // workspace layout (~218 MB total)
  float* xq = (float*)d_ws;                                   // 16384*128 f32
  float* xk = xq + (size_t)BN_ * 128;
  float* xv = xk + (size_t)BN_ * 128;
  int*   knn = (int*)(xv + (size_t)BN_ * 128);                // 16384*16 i32
  unsigned short* W1f = (unsigned short*)(knn + (size_t)BN_ * 16);  // 32768 bf16
  unsigned short* W2f = W1f + 32768;                          // 32768 bf16
  unsigned short* Hf  = W2f + 32768;                          // 16384*4*512 bf16 (67 MB)
  float* VPEf = (float*)(Hf + (size_t)BN_ * 4 * 512);         // 16384*8*256 f32 (134 MB)

  wshuf_kernel<<<16, 256, 0, stream>>>(a_w1, a_w2, W1f, W2f);
  qkv_kernel<<<BN_ / 32, 256, 0, stream>>>(x, Wq, Wk, Wv, xq, xk, xv);
  knn_kernel<<<BN_ / 4, 256, 0, stream>>>(pos, knn);
  build_kernel<<<BN_ / 4, 256, 0, stream>>>(pos, xq, xk, xv, knn,
                                            p_w1, p_b1, p_w2, p_b2, Hf, VPEf);
  mlp_kernel<<<BN_ / 8, 512, 0, stream>>>(Hf, W1f, W2f, a_b1, a_b2, VPEf, out);
}